// Round 12
// baseline (2647.448 us; speedup 1.0000x reference)
//
#include <hip/hip_runtime.h>
#include <stdint.h>

#define NN_NODE 50000
#define NN_EDGE 800000

typedef _Float16 f16;
typedef _Float16 f16x2 __attribute__((ext_vector_type(2)));
typedef _Float16 f16x4 __attribute__((ext_vector_type(4)));
typedef _Float16 f16x8 __attribute__((ext_vector_type(8)));
typedef float f32x4 __attribute__((ext_vector_type(4)));

// ---- workspace layout ----
#define WT_MW0   0        // [256][32]  (K=10 padded to 32)
#define WT_MW1   8192     // [256][256]
#define WT_MW2   73728    // [128][256]
#define WT_AW0   106496   // [128][128]
#define WT_AW1   122880   // [128][128]
#define WT_VW0   139264   // [256][128]
#define WT_VW1   172032   // [128][256]
#define WT_UW0   204800   // [256][128]
#define WT_UW1   237568   // [256][256]
#define WT_TOTAL 303104

#define V_OFF      606208ull                  // f16 v[E][128]   (receiver-sorted)
#define WL_OFF     205406208ull               // float wlog[E]   (receiver-sorted)
#define CNT_OFF    208606208ull               // int cnt/cursor[N]
#define BASE_OFF   208806208ull               // int base[N]
#define AGGR_OFF   209006208ull               // float aggr[N][128]

// XOR-swizzled LDS addressing: rows of 256 f16 = 32 chunks of 8 f16 (16B).
__device__ __forceinline__ int swz(int row, int col) {
    return row * 256 + ((((col >> 3) ^ (row & 7))) << 3) + (col & 7);
}

// ---- edge-split wave-private fused MLP layer (R12 = R10 at (256,2)) ----
// Each WAVE owns 16 edges (ONE m-tile) x ALL N output feats, with a private
// 16x256 f16 LDS slice (8KB). ZERO barriers: the wave reads back only what
// it wrote (same-wave LDS is in-order; all kc-loop reads precede epilogue
// writes -> in-place safe, no fence). af reads drop 4x vs feat-split.
// Waves free-run across layers -> one wave's W-load stall overlaps another
// wave's MFMAs (the overlap every barriered variant forbade).
//
// R10 tested this at launch_bounds(256,4): the 64-VGPR wall spilled
// (FETCH 826MB). At (256,2) the budget is ~128 VGPR + AGPR-backed acc:
// acc[NCT]<=64 (AGPR), af<=16 + W dbuf 32 + addr ~15 VGPR -> no spill,
// ~3 waves/SIMD by unified-file arithmetic.
// Cost: full weight stream per wave (4x); same-block waves run identical
// instruction streams near-lockstep -> L1 absorbs most of the 4x.
//
// MFMA: A = weight W^T[n][k], B = activations; D: col=edge=lane&15,
// row=feat=quad*4+reg. Bias folded into acc init.
// EPI: 0 = relu -> LDS slice; 1 = logit (dot aw2, quad-reduce, per-edge
//      atomicAdd by quad0 lanes, pos kept in register); 2 = relu -> global
//      v-store at slot (shfl-broadcast from quad0).
template<int K, int N, int EPI>
__device__ __forceinline__ void mlayerM(f16* sl, int inoff, int outoff,
        const f16* __restrict__ wt, const float* __restrict__ bias,
        const float* __restrict__ aw2, const float* __restrict__ ab2,
        float* __restrict__ wlog, int* __restrict__ cursor,
        const int* __restrict__ receivers, int e0w,
        f16* __restrict__ vout, int& pos, int lane)
{
    const int l15  = lane & 15;
    const int quad = lane >> 4;
    constexpr int NKS = K >> 5;                 // 1,4,8
    constexpr int NKC = (NKS > 4) ? 2 : 1;      // K-chunks
    constexpr int KCS = NKS / NKC;              // slices per chunk (1..4)
    constexpr int NCT = N >> 4;                 // 8 or 16

    // accumulators for ALL N feats of this wave's 16 edges, bias-init
    f32x4 acc[NCT];
#pragma unroll
    for (int ct = 0; ct < NCT; ++ct) {
        const float4 bv = *(const float4*)(bias + ct * 16 + quad * 4);
        acc[ct] = (f32x4){bv.x, bv.y, bv.z, bv.w};
    }

#pragma unroll
    for (int kc = 0; kc < NKC; ++kc) {
        // af for this K-chunk: 1 m-tile only (4x fewer LDS reads than
        // feat-split). Read once, pinned.
        f16x8 af[KCS];
#pragma unroll
        for (int s = 0; s < KCS; ++s)
            af[s] = *(const f16x8*)(sl + swz(l15,
                            inoff + (kc * KCS + s) * 32 + quad * 8));
#pragma unroll
        for (int s = 0; s < KCS; ++s)
            asm volatile("" : "+v"(af[s]));

        // stream W over all NCT ct-tiles with a 1-deep double buffer
        f16x8 W[2][KCS];
        {
            const f16* wr = wt + (size_t)l15 * K + kc * KCS * 32 + quad * 8;
#pragma unroll
            for (int s = 0; s < KCS; ++s) W[0][s] = *(const f16x8*)(wr + s * 32);
        }
#pragma unroll
        for (int ct = 0; ct < NCT; ++ct) {
            if (ct + 1 < NCT) {
                const f16* wr = wt + (size_t)((ct + 1) * 16 + l15) * K
                                + kc * KCS * 32 + quad * 8;
#pragma unroll
                for (int s = 0; s < KCS; ++s)
                    W[(ct + 1) & 1][s] = *(const f16x8*)(wr + s * 32);
            }
#pragma unroll
            for (int s = 0; s < KCS; ++s)
                acc[ct] = __builtin_amdgcn_mfma_f32_16x16x32_f16(
                    W[ct & 1][s], af[s], acc[ct], 0, 0, 0);
        }
    }

    // ---- epilogue (wave-private slice: in-order LDS -> no fence) ----
    if constexpr (EPI == 0) {
#pragma unroll
        for (int ct = 0; ct < NCT; ++ct) {
            f16x4 o;
            o[0] = (f16)fmaxf(acc[ct][0], 0.f);
            o[1] = (f16)fmaxf(acc[ct][1], 0.f);
            o[2] = (f16)fmaxf(acc[ct][2], 0.f);
            o[3] = (f16)fmaxf(acc[ct][3], 0.f);
            *(f16x4*)(sl + swz(l15, outoff + ct * 16 + quad * 4)) = o;
        }
    } else if constexpr (EPI == 1) {
        float p = 0.f;
#pragma unroll
        for (int ct = 0; ct < NCT; ++ct) {
            const float4 awv = *(const float4*)(aw2 + ct * 16 + quad * 4);
            p += fmaxf(acc[ct][0], 0.f) * awv.x
               + fmaxf(acc[ct][1], 0.f) * awv.y
               + fmaxf(acc[ct][2], 0.f) * awv.z
               + fmaxf(acc[ct][3], 0.f) * awv.w;
        }
        p += __shfl_xor(p, 16);
        p += __shfl_xor(p, 32);
        pos = 0;
        if (quad == 0) {   // 16 lanes, one per edge
            float lg = p + ab2[0];
            int ge = e0w + l15;
            int r = receivers[ge];
            pos = atomicAdd(&cursor[r], 1);
            wlog[pos] = lg;
        }
    } else {   // EPI == 2: v direct to global at receiver-sorted slot
        const int slot = __shfl(pos, l15);   // from quad0 lane l15
#pragma unroll
        for (int ct = 0; ct < NCT; ++ct) {
            f16x4 o;
            o[0] = (f16)fmaxf(acc[ct][0], 0.f);
            o[1] = (f16)fmaxf(acc[ct][1], 0.f);
            o[2] = (f16)fmaxf(acc[ct][2], 0.f);
            o[3] = (f16)fmaxf(acc[ct][3], 0.f);
            *(f16x4*)(vout + (size_t)slot * 128 + ct * 16 + quad * 4) = o;
        }
    }
}

// ---- simple layer variant (node_kernel) ----
template<int K, int N>
__device__ __forceinline__ void mfma_layer_basic(const f16* in, int inoff,
        const f16* __restrict__ wt, const float* __restrict__ bias,
        f16* out, int outoff, int tid)
{
    const int wave = tid >> 6;
    const int lane = tid & 63;
    const int l15  = lane & 15;
    const int quad = lane >> 4;
    constexpr int NCT = N >> 4;
    constexpr int NKS = K >> 5;
    f16x8 af[4][NKS];
#pragma unroll
    for (int ms = 0; ms < 4; ++ms)
#pragma unroll
        for (int ks = 0; ks < NKS; ++ks)
            af[ms][ks] = *(const f16x8*)(in + swz(ms * 16 + l15, inoff + ks * 32 + quad * 8));
#pragma unroll 1
    for (int ct = wave; ct < NCT; ct += 4) {
        f16x8 bf[NKS];
        const f16* wrow = wt + (size_t)(ct * 16 + l15) * K + quad * 8;
#pragma unroll
        for (int ks = 0; ks < NKS; ++ks) bf[ks] = *(const f16x8*)(wrow + ks * 32);
        const int f0 = ct * 16 + quad * 4;
        const float4 bv = *(const float4*)(bias + f0);
#pragma unroll
        for (int ms = 0; ms < 4; ++ms) {
            f32x4 acc = {0.f, 0.f, 0.f, 0.f};
#pragma unroll
            for (int ks = 0; ks < NKS; ++ks)
                acc = __builtin_amdgcn_mfma_f32_16x16x32_f16(bf[ks], af[ms][ks], acc, 0, 0, 0);
            f16x4 o;
            o[0] = (f16)fmaxf(acc[0] + bv.x, 0.f);
            o[1] = (f16)fmaxf(acc[1] + bv.y, 0.f);
            o[2] = (f16)fmaxf(acc[2] + bv.z, 0.f);
            o[3] = (f16)fmaxf(acc[3] + bv.w, 0.f);
            *(f16x4*)(out + swz(ms * 16 + l15, outoff + f0)) = o;
        }
    }
}

// ---- prep: transpose-convert weights to f16 [N][Kpad] ----
struct WSeg { const float* src; int K, N, Kpad, dstOff; };
struct WSegs { WSeg s[9]; };

__global__ void prep_kernel(WSegs segs, f16* __restrict__ wt) {
    int idx = blockIdx.x * 256 + threadIdx.x;
    if (idx >= WT_TOTAL) return;
    int off = idx;
#pragma unroll
    for (int i = 0; i < 9; ++i) {
        int sz = segs.s[i].N * segs.s[i].Kpad;
        if (off < sz) {
            int n = off / segs.s[i].Kpad;
            int k = off - n * segs.s[i].Kpad;
            f16 val = (f16)0.f;
            if (k < segs.s[i].K) val = (f16)segs.s[i].src[k * segs.s[i].N + n];
            wt[segs.s[i].dstOff + off] = val;
            return;
        }
        off -= sz;
    }
}

// ---- sort step 1: histogram of receivers ----
__global__ void hist_kernel(const int* __restrict__ receivers, int* __restrict__ cnt) {
    int e = blockIdx.x * 256 + threadIdx.x;
    atomicAdd(&cnt[receivers[e]], 1);
}

// ---- sort step 2: exclusive scan ----
__global__ __launch_bounds__(1024) void scan_kernel(int* __restrict__ cnt, int* __restrict__ base) {
    __shared__ int psum[1024];
    const int tid = threadIdx.x;
    const int CH = (NN_NODE + 1023) / 1024;
    const int lo = tid * CH;
    const int hi = min(lo + CH, NN_NODE);
    int s = 0;
    for (int i = lo; i < hi; ++i) s += cnt[i];
    psum[tid] = s;
    __syncthreads();
    for (int d = 1; d < 1024; d <<= 1) {
        int v = (tid >= d) ? psum[tid - d] : 0;
        __syncthreads();
        psum[tid] += v;
        __syncthreads();
    }
    int run = psum[tid] - s;
    for (int i = lo; i < hi; ++i) {
        int c = cnt[i];
        base[i] = run;
        cnt[i] = run;
        run += c;
    }
}

// ---- K1: per-edge encoder + attention logit + value ----
// 256 threads = 4 waves; each wave owns 16 edges + an 8KB private LDS
// slice. ZERO __syncthreads. launch_bounds(256,2): ~128 VGPR budget so the
// working set does NOT spill (R10's failure mode at (256,4)/64-VGPR).
__global__ __launch_bounds__(256, 2) void edge_kernel(
        const float* __restrict__ nodes, const float* __restrict__ edges,
        const int* __restrict__ senders, const int* __restrict__ receivers,
        const f16* __restrict__ wt,
        const float* __restrict__ mb0, const float* __restrict__ mb1, const float* __restrict__ mb2,
        const float* __restrict__ ab0, const float* __restrict__ ab1,
        const float* __restrict__ aw2, const float* __restrict__ ab2,
        const float* __restrict__ vb0, const float* __restrict__ vb1,
        f16* __restrict__ vout, float* __restrict__ wlog, int* __restrict__ cursor)
{
    __shared__ f16 buf[4 * 16 * 256];   // 32 KB = 4 private 8KB slices
    const int tid  = threadIdx.x;
    const int wave = tid >> 6;
    const int lane = tid & 63;
    f16* sl = buf + wave * 16 * 256;
    const int e0w = blockIdx.x * 64 + wave * 16;

    // stage z into own slice: 16 rows x 32 cols (K=10 padded to 32).
    // lane = row (l15) x chunk (quad): chunk0=[s.xyz,r.xyz,e01],
    // chunk1=[e23,0...], chunk2/3=0.
    {
        const int r = lane & 15;
        const int c = lane >> 4;
        const int ge = e0w + r;
        f16x8 zv = {(f16)0.f,(f16)0.f,(f16)0.f,(f16)0.f,(f16)0.f,(f16)0.f,(f16)0.f,(f16)0.f};
        if (c == 0) {
            int s = senders[ge];
            int rc = receivers[ge];
            const float2 ev = *(const float2*)(edges + (size_t)ge * 4);
            zv[0] = (f16)nodes[s * 3 + 0]; zv[1] = (f16)nodes[s * 3 + 1]; zv[2] = (f16)nodes[s * 3 + 2];
            zv[3] = (f16)nodes[rc * 3 + 0]; zv[4] = (f16)nodes[rc * 3 + 1]; zv[5] = (f16)nodes[rc * 3 + 2];
            zv[6] = (f16)ev.x; zv[7] = (f16)ev.y;
        } else if (c == 1) {
            const float2 ev = *(const float2*)(edges + (size_t)ge * 4 + 2);
            zv[0] = (f16)ev.x; zv[1] = (f16)ev.y;
        }
        *(f16x8*)(sl + swz(r, c * 8)) = zv;
    }
    // no barrier: slice is wave-private, same-wave LDS is in-order

    int pos = 0;
    // L1: z(0-31) -> a1(0-255)
    mlayerM< 32, 256, 0>(sl, 0, 0, wt + WT_MW0, mb0, nullptr, nullptr,
                         nullptr, nullptr, nullptr, 0, nullptr, pos, lane);
    // MW1: a1 -> a2 (0-255), in-place
    mlayerM<256, 256, 0>(sl, 0, 0, wt + WT_MW1, mb1, nullptr, nullptr,
                         nullptr, nullptr, nullptr, 0, nullptr, pos, lane);
    // MW2: a2 -> q (0-127), in-place
    mlayerM<256, 128, 0>(sl, 0, 0, wt + WT_MW2, mb2, nullptr, nullptr,
                         nullptr, nullptr, nullptr, 0, nullptr, pos, lane);
    // AW0: q(0-127) -> h0(128-255)
    mlayerM<128, 128, 0>(sl, 0, 128, wt + WT_AW0, ab0, nullptr, nullptr,
                         nullptr, nullptr, nullptr, 0, nullptr, pos, lane);
    // AW1: h0 -> logits (per-edge atomic slot, pos in register)
    mlayerM<128, 128, 1>(sl, 128, 0, wt + WT_AW1, ab1, aw2, ab2,
                         wlog, cursor, receivers, e0w, nullptr, pos, lane);
    // VW0: q(0-127) -> v1(0-255)
    mlayerM<128, 256, 0>(sl, 0, 0, wt + WT_VW0, vb0, nullptr, nullptr,
                         nullptr, nullptr, nullptr, 0, nullptr, pos, lane);
    // VW1: v1 -> v (global, receiver-sorted slots)
    mlayerM<256, 128, 2>(sl, 0, 0, wt + WT_VW1, vb1, nullptr, nullptr,
                         nullptr, nullptr, nullptr, 0, vout, pos, lane);
}

// ---- K2: per-node segmented softmax + weighted aggregation ----
// 4 edges x 128 feats per iteration (1KB/wave/iter); lane (quad,l15) owns
// edge-slot quad, feature octet l15; cross-quad shfl reduce at the end.
__global__ __launch_bounds__(256) void aggregate_kernel(
        const float* __restrict__ wlog, const f16* __restrict__ v,
        const int* __restrict__ base, float* __restrict__ aggr)
{
    const int tid = threadIdx.x;
    const int n = blockIdx.x * 4 + (tid >> 6);
    const int lane = tid & 63;
    const int l15  = lane & 15;
    const int quad = lane >> 4;
    const int st = base[n];
    const int en = (n == NN_NODE - 1) ? NN_EDGE : base[n + 1];

    float mx = -1e9f;
    for (int i = st + lane; i < en; i += 64) mx = fmaxf(mx, wlog[i]);
#pragma unroll
    for (int d = 1; d < 64; d <<= 1) mx = fmaxf(mx, __shfl_xor(mx, d));

    float sm = 0.f;
    for (int i = st + lane; i < en; i += 64) sm += __expf(wlog[i] - mx);
#pragma unroll
    for (int d = 1; d < 64; d <<= 1) sm += __shfl_xor(sm, d);
    const float inv = 1.f / (sm + 1e-12f);

    float a0 = 0.f, a1 = 0.f, a2 = 0.f, a3 = 0.f;
    float a4 = 0.f, a5 = 0.f, a6 = 0.f, a7 = 0.f;
    for (int i = st + quad; i < en; i += 4) {
        float attn = __expf(wlog[i] - mx) * inv;
        f16x8 vv = *(const f16x8*)(v + (size_t)i * 128 + l15 * 8);
        a0 += attn * (float)vv[0];
        a1 += attn * (float)vv[1];
        a2 += attn * (float)vv[2];
        a3 += attn * (float)vv[3];
        a4 += attn * (float)vv[4];
        a5 += attn * (float)vv[5];
        a6 += attn * (float)vv[6];
        a7 += attn * (float)vv[7];
    }
    a0 += __shfl_xor(a0, 16); a0 += __shfl_xor(a0, 32);
    a1 += __shfl_xor(a1, 16); a1 += __shfl_xor(a1, 32);
    a2 += __shfl_xor(a2, 16); a2 += __shfl_xor(a2, 32);
    a3 += __shfl_xor(a3, 16); a3 += __shfl_xor(a3, 32);
    a4 += __shfl_xor(a4, 16); a4 += __shfl_xor(a4, 32);
    a5 += __shfl_xor(a5, 16); a5 += __shfl_xor(a5, 32);
    a6 += __shfl_xor(a6, 16); a6 += __shfl_xor(a6, 32);
    a7 += __shfl_xor(a7, 16); a7 += __shfl_xor(a7, 32);
    if (quad == 0) {
        float4 o0; o0.x = a0; o0.y = a1; o0.z = a2; o0.w = a3;
        float4 o1; o1.x = a4; o1.y = a5; o1.z = a6; o1.w = a7;
        float* dst = aggr + (size_t)n * 128 + l15 * 8;
        *(float4*)(dst + 0) = o0;
        *(float4*)(dst + 4) = o1;
    }
}

// ---- K3: node decoder (64-node tiles) ----
__global__ __launch_bounds__(256, 2) void node_kernel(
        const float* __restrict__ aggr, const f16* __restrict__ wt,
        const float* __restrict__ ub0, const float* __restrict__ ub1,
        const float* __restrict__ uw2, const float* __restrict__ ub2,
        float* __restrict__ out)
{
    __shared__ f16 ldsbuf[2 * 64 * 256];
    f16* bufA = ldsbuf;
    f16* bufB = ldsbuf + 64 * 256;
    const int tid = threadIdx.x;
    const int n0 = blockIdx.x * 64;
    {
        int row = tid >> 2, j = tid & 3;
        int n = n0 + row;
        if (n < NN_NODE) {
            const float4* src = (const float4*)(aggr + (size_t)n * 128 + j * 32);
#pragma unroll
            for (int i = 0; i < 8; ++i) {
                float4 t4 = src[i];
                int c = j * 32 + i * 4;
                bufA[swz(row, c + 0)] = (f16)t4.x;
                bufA[swz(row, c + 1)] = (f16)t4.y;
                bufA[swz(row, c + 2)] = (f16)t4.z;
                bufA[swz(row, c + 3)] = (f16)t4.w;
            }
        } else {
#pragma unroll
            for (int i = 0; i < 32; ++i) bufA[swz(row, j * 32 + i)] = (f16)0.f;
        }
    }
    __syncthreads();
    mfma_layer_basic<128, 256>(bufA, 0, wt + WT_UW0, ub0, bufB, 0, tid); __syncthreads();
    mfma_layer_basic<256, 256>(bufB, 0, wt + WT_UW1, ub1, bufA, 0, tid); __syncthreads();
    {
        int e = tid >> 2, part = tid & 3;
        float sum = 0.f;
        for (int c = part * 64; c < part * 64 + 64; ++c)
            sum += (float)bufA[swz(e, c)] * uw2[c];
        sum += __shfl_down(sum, 2);
        sum += __shfl_down(sum, 1);
        int n = n0 + e;
        if (part == 0 && n < NN_NODE) out[n] = sum + ub2[0];
    }
}

extern "C" void kernel_launch(void* const* d_in, const int* in_sizes, int n_in,
                              void* d_out, int out_size, void* d_ws, size_t ws_size,
                              hipStream_t stream)
{
    const float* nodes     = (const float*)d_in[0];
    const float* edges     = (const float*)d_in[1];
    const int*   senders   = (const int*)d_in[2];
    const int*   receivers = (const int*)d_in[3];
    const float* mw0 = (const float*)d_in[4];  const float* mb0 = (const float*)d_in[5];
    const float* mw1 = (const float*)d_in[6];  const float* mb1 = (const float*)d_in[7];
    const float* mw2 = (const float*)d_in[8];  const float* mb2 = (const float*)d_in[9];
    const float* aw0 = (const float*)d_in[10]; const float* ab0 = (const float*)d_in[11];
    const float* aw1 = (const float*)d_in[12]; const float* ab1 = (const float*)d_in[13];
    const float* aw2 = (const float*)d_in[14]; const float* ab2 = (const float*)d_in[15];
    const float* vw0 = (const float*)d_in[16]; const float* vb0 = (const float*)d_in[17];
    const float* vw1 = (const float*)d_in[18]; const float* vb1 = (const float*)d_in[19];
    const float* uw0 = (const float*)d_in[20]; const float* ub0 = (const float*)d_in[21];
    const float* uw1 = (const float*)d_in[22]; const float* ub1 = (const float*)d_in[23];
    const float* uw2 = (const float*)d_in[24]; const float* ub2 = (const float*)d_in[25];

    char* ws = (char*)d_ws;
    f16*   wt   = (f16*)ws;
    f16*   vbuf = (f16*)(ws + V_OFF);
    float* wlog = (float*)(ws + WL_OFF);
    int*   cnt  = (int*)(ws + CNT_OFF);
    int*   base = (int*)(ws + BASE_OFF);
    float* aggr = (float*)(ws + AGGR_OFF);
    float* out  = (float*)d_out;

    hipMemsetAsync(cnt, 0, NN_NODE * sizeof(int), stream);

    WSegs segs = {{
        { mw0,  10, 256,  32, WT_MW0 },
        { mw1, 256, 256, 256, WT_MW1 },
        { mw2, 256, 128, 256, WT_MW2 },
        { aw0, 128, 128, 128, WT_AW0 },
        { aw1, 128, 128, 128, WT_AW1 },
        { vw0, 128, 256, 128, WT_VW0 },
        { vw1, 256, 128, 256, WT_VW1 },
        { uw0, 128, 256, 128, WT_UW0 },
        { uw1, 256, 256, 256, WT_UW1 },
    }};
    prep_kernel<<<(WT_TOTAL + 255) / 256, 256, 0, stream>>>(segs, wt);

    hist_kernel<<<NN_EDGE / 256, 256, 0, stream>>>(receivers, cnt);
    scan_kernel<<<1, 1024, 0, stream>>>(cnt, base);

    edge_kernel<<<NN_EDGE / 64, 256, 0, stream>>>(nodes, edges, senders, receivers, wt,
        mb0, mb1, mb2, ab0, ab1, aw2, ab2, vb0, vb1, vbuf, wlog, cnt);

    aggregate_kernel<<<NN_NODE / 4, 256, 0, stream>>>(wlog, vbuf, base, aggr);

    node_kernel<<<(NN_NODE + 63) / 64, 256, 0, stream>>>(aggr, wt, ub0, ub1, uw2, ub2, out);
}

// Round 13
// 955.299 us; speedup vs baseline: 2.7713x; 2.7713x over previous
//
#include <hip/hip_runtime.h>
#include <stdint.h>

#define NN_NODE 50000
#define NN_EDGE 800000

typedef _Float16 f16;
typedef _Float16 f16x2 __attribute__((ext_vector_type(2)));
typedef _Float16 f16x4 __attribute__((ext_vector_type(4)));
typedef _Float16 f16x8 __attribute__((ext_vector_type(8)));
typedef float f32x4 __attribute__((ext_vector_type(4)));

// ---- workspace layout ----
#define WT_MW0   0        // [256][32]  (K=10 padded to 32)
#define WT_MW1   8192     // [256][256]
#define WT_MW2   73728    // [128][256]
#define WT_AW0   106496   // [128][128]
#define WT_AW1   122880   // [128][128]
#define WT_VW0   139264   // [256][128]
#define WT_VW1   172032   // [128][256]
#define WT_UW0   204800   // [256][128]
#define WT_UW1   237568   // [256][256]
#define WT_TOTAL 303104

#define V_OFF      606208ull                  // f16 v[E][128]   (receiver-sorted)
#define WL_OFF     205406208ull               // float wlog[E]   (receiver-sorted)
#define CNT_OFF    208606208ull               // int cnt/cursor[N]
#define BASE_OFF   208806208ull               // int base[N]
#define AGGR_OFF   209006208ull               // float aggr[N][128]

// XOR-swizzled LDS addressing: rows of 256 f16 = 32 chunks of 8 f16 (16B).
__device__ __forceinline__ int swz(int row, int col) {
    return row * 256 + ((((col >> 3) ^ (row & 7))) << 3) + (col & 7);
}

// ---- register-lean fused MLP layer (best measured form: 692us edge,
// VGPR 64, no spill, 16 waves/CU) ----
// Session lesson bank (R0-R12):
//  - feat-split + barriers: 692us regardless of pipelining depth or
//    occupancy (8 or 16 waves) — composition equilibrium: MFMA ~23%,
//    VALU ~23%, LDS ~45%, L2-weights ~21% chained serially per wave.
//  - >64-VGPR live sets under launch_bounds(256,4) spill (R2/R9/R10);
//    (256,2) gives ~124 VGPR but only 8 waves (R3: same 692).
//  - wave-autonomous / edge-split variants lose 4x arithmetic intensity
//    per weight byte -> weight-stream bound, 2-3.5x slower (R6/R12).
template<int K, int N, int EPI, int IBAR>
__device__ __forceinline__ void mlayerR(f16* buf, int inoff, int outoff,
        const f16* __restrict__ wt, const float* __restrict__ bias,
        const float* __restrict__ aw2, float* lpart,
        f16* __restrict__ vout, const int* sposp, int tid)
{
    const int wave = tid >> 6;
    const int lane = tid & 63;
    const int l15  = lane & 15;
    const int quad = lane >> 4;
    constexpr int KS = (K >= 64) ? 2 : 1;     // k-slices per chunk
    constexpr int KC = KS * 32;               // chunk width (64 or 32)
    constexpr int NC = K / KC;                // chunks (1,2,4)
    constexpr int C  = (N >> 4) / 4;          // ct-tiles per wave (2 or 4)

    f32x4 acc[C][4];
#pragma unroll
    for (int ci = 0; ci < C; ++ci)
#pragma unroll
        for (int m = 0; m < 4; ++m)
            acc[ci][m] = (f32x4){0.f, 0.f, 0.f, 0.f};

#pragma unroll 1
    for (int kc = 0; kc < NC; ++kc) {
        // af chunk: 4 m-tiles x KS slices (32 VGPR), read once, pinned
        f16x8 af[4][KS];
#pragma unroll
        for (int m = 0; m < 4; ++m)
#pragma unroll
            for (int ks = 0; ks < KS; ++ks)
                af[m][ks] = *(const f16x8*)(buf + swz(m * 16 + l15,
                                    inoff + kc * KC + ks * 32 + quad * 8));
#pragma unroll
        for (int m = 0; m < 4; ++m)
#pragma unroll
            for (int ks = 0; ks < KS; ++ks)
                asm volatile("" : "+v"(af[m][ks]));

#pragma unroll
        for (int ci = 0; ci < C; ++ci) {
            const int ct = wave + ci * 4;
            f16x8 W[KS];
            const f16* wr = wt + (size_t)(ct * 16 + l15) * K + kc * KC + quad * 8;
#pragma unroll
            for (int ks = 0; ks < KS; ++ks) W[ks] = *(const f16x8*)(wr + ks * 32);
#pragma unroll
            for (int m = 0; m < 4; ++m)
#pragma unroll
                for (int ks = 0; ks < KS; ++ks)
                    acc[ci][m] = __builtin_amdgcn_mfma_f32_16x16x32_f16(
                        W[ks], af[m][ks], acc[ci][m], 0, 0, 0);
        }
    }

    // cross-wave WAR fence for in-place update
    if constexpr (IBAR) __syncthreads();

    // ---- epilogue ----
    float preg[4];
    if constexpr (EPI == 1) {
#pragma unroll
        for (int m = 0; m < 4; ++m) preg[m] = 0.f;
    }
    int sposv[4];
    if constexpr (EPI == 2) {
#pragma unroll
        for (int m = 0; m < 4; ++m) sposv[m] = sposp[m * 16 + l15];
    }
#pragma unroll
    for (int ci = 0; ci < C; ++ci) {
        const int ct = wave + ci * 4;
        const int f0 = ct * 16 + quad * 4;
        const float4 bv = *(const float4*)(bias + f0);
        float4 awv;
        if constexpr (EPI == 1) awv = *(const float4*)(aw2 + f0);
#pragma unroll
        for (int m = 0; m < 4; ++m) {
            if constexpr (EPI == 0) {
                f16x4 o;
                o[0] = (f16)fmaxf(acc[ci][m][0] + bv.x, 0.f);
                o[1] = (f16)fmaxf(acc[ci][m][1] + bv.y, 0.f);
                o[2] = (f16)fmaxf(acc[ci][m][2] + bv.z, 0.f);
                o[3] = (f16)fmaxf(acc[ci][m][3] + bv.w, 0.f);
                *(f16x4*)(buf + swz(m * 16 + l15, outoff + f0)) = o;
            } else if constexpr (EPI == 1) {
                preg[m] += fmaxf(acc[ci][m][0] + bv.x, 0.f) * awv.x
                         + fmaxf(acc[ci][m][1] + bv.y, 0.f) * awv.y
                         + fmaxf(acc[ci][m][2] + bv.z, 0.f) * awv.z
                         + fmaxf(acc[ci][m][3] + bv.w, 0.f) * awv.w;
            } else {
                f16x4 o;
                o[0] = (f16)fmaxf(acc[ci][m][0] + bv.x, 0.f);
                o[1] = (f16)fmaxf(acc[ci][m][1] + bv.y, 0.f);
                o[2] = (f16)fmaxf(acc[ci][m][2] + bv.z, 0.f);
                o[3] = (f16)fmaxf(acc[ci][m][3] + bv.w, 0.f);
                *(f16x4*)(vout + (size_t)sposv[m] * 128 + f0) = o;
            }
        }
    }
    if constexpr (EPI == 1) {
#pragma unroll
        for (int m = 0; m < 4; ++m) {
            float r = preg[m];
            r += __shfl_xor(r, 16);
            r += __shfl_xor(r, 32);
            if (quad == 0) lpart[wave * 64 + m * 16 + l15] = r;
        }
    }
}

// ---- simple layer variant (node_kernel) ----
template<int K, int N>
__device__ __forceinline__ void mfma_layer_basic(const f16* in, int inoff,
        const f16* __restrict__ wt, const float* __restrict__ bias,
        f16* out, int outoff, int tid)
{
    const int wave = tid >> 6;
    const int lane = tid & 63;
    const int l15  = lane & 15;
    const int quad = lane >> 4;
    constexpr int NCT = N >> 4;
    constexpr int NKS = K >> 5;
    f16x8 af[4][NKS];
#pragma unroll
    for (int ms = 0; ms < 4; ++ms)
#pragma unroll
        for (int ks = 0; ks < NKS; ++ks)
            af[ms][ks] = *(const f16x8*)(in + swz(ms * 16 + l15, inoff + ks * 32 + quad * 8));
#pragma unroll 1
    for (int ct = wave; ct < NCT; ct += 4) {
        f16x8 bf[NKS];
        const f16* wrow = wt + (size_t)(ct * 16 + l15) * K + quad * 8;
#pragma unroll
        for (int ks = 0; ks < NKS; ++ks) bf[ks] = *(const f16x8*)(wrow + ks * 32);
        const int f0 = ct * 16 + quad * 4;
        const float4 bv = *(const float4*)(bias + f0);
#pragma unroll
        for (int ms = 0; ms < 4; ++ms) {
            f32x4 acc = {0.f, 0.f, 0.f, 0.f};
#pragma unroll
            for (int ks = 0; ks < NKS; ++ks)
                acc = __builtin_amdgcn_mfma_f32_16x16x32_f16(bf[ks], af[ms][ks], acc, 0, 0, 0);
            f16x4 o;
            o[0] = (f16)fmaxf(acc[0] + bv.x, 0.f);
            o[1] = (f16)fmaxf(acc[1] + bv.y, 0.f);
            o[2] = (f16)fmaxf(acc[2] + bv.z, 0.f);
            o[3] = (f16)fmaxf(acc[3] + bv.w, 0.f);
            *(f16x4*)(out + swz(ms * 16 + l15, outoff + f0)) = o;
        }
    }
}

// ---- prep: transpose-convert weights to f16 [N][Kpad] ----
struct WSeg { const float* src; int K, N, Kpad, dstOff; };
struct WSegs { WSeg s[9]; };

__global__ void prep_kernel(WSegs segs, f16* __restrict__ wt) {
    int idx = blockIdx.x * 256 + threadIdx.x;
    if (idx >= WT_TOTAL) return;
    int off = idx;
#pragma unroll
    for (int i = 0; i < 9; ++i) {
        int sz = segs.s[i].N * segs.s[i].Kpad;
        if (off < sz) {
            int n = off / segs.s[i].Kpad;
            int k = off - n * segs.s[i].Kpad;
            f16 val = (f16)0.f;
            if (k < segs.s[i].K) val = (f16)segs.s[i].src[k * segs.s[i].N + n];
            wt[segs.s[i].dstOff + off] = val;
            return;
        }
        off -= sz;
    }
}

// ---- sort step 1: histogram of receivers ----
__global__ void hist_kernel(const int* __restrict__ receivers, int* __restrict__ cnt) {
    int e = blockIdx.x * 256 + threadIdx.x;
    atomicAdd(&cnt[receivers[e]], 1);
}

// ---- sort step 2: exclusive scan ----
__global__ __launch_bounds__(1024) void scan_kernel(int* __restrict__ cnt, int* __restrict__ base) {
    __shared__ int psum[1024];
    const int tid = threadIdx.x;
    const int CH = (NN_NODE + 1023) / 1024;
    const int lo = tid * CH;
    const int hi = min(lo + CH, NN_NODE);
    int s = 0;
    for (int i = lo; i < hi; ++i) s += cnt[i];
    psum[tid] = s;
    __syncthreads();
    for (int d = 1; d < 1024; d <<= 1) {
        int v = (tid >= d) ? psum[tid - d] : 0;
        __syncthreads();
        psum[tid] += v;
        __syncthreads();
    }
    int run = psum[tid] - s;
    for (int i = lo; i < hi; ++i) {
        int c = cnt[i];
        base[i] = run;
        cnt[i] = run;
        run += c;
    }
}

// ---- K1: per-edge encoder + attention logit + value; 64 edges/block ----
// Single 32KB in-place buffer, 4 blocks/CU, 16 waves/CU.
__global__ __launch_bounds__(256, 4) void edge_kernel(
        const float* __restrict__ nodes, const float* __restrict__ edges,
        const int* __restrict__ senders, const int* __restrict__ receivers,
        const f16* __restrict__ wt,
        const float* __restrict__ mb0, const float* __restrict__ mb1, const float* __restrict__ mb2,
        const float* __restrict__ ab0, const float* __restrict__ ab1,
        const float* __restrict__ aw2, const float* __restrict__ ab2,
        const float* __restrict__ vb0, const float* __restrict__ vb1,
        f16* __restrict__ vout, float* __restrict__ wlog, int* __restrict__ cursor)
{
    __shared__ f16 buf[64 * 256];   // 32 KB
    __shared__ int spos[64];
    __shared__ float lpart[256];
    const int tid = threadIdx.x;
    const int e0 = blockIdx.x * 64;

    // stage z: one b128 write per thread. Thread (e, c) owns chunk c of row e.
    {
        const int e = tid & 63, c = tid >> 6;
        f16x8 zv = {(f16)0.f,(f16)0.f,(f16)0.f,(f16)0.f,(f16)0.f,(f16)0.f,(f16)0.f,(f16)0.f};
        if (c == 0) {
            int s = senders[e0 + e];
            int r = receivers[e0 + e];
            const float2 ev = *(const float2*)(edges + (size_t)(e0 + e) * 4);
            zv[0] = (f16)nodes[s * 3 + 0]; zv[1] = (f16)nodes[s * 3 + 1]; zv[2] = (f16)nodes[s * 3 + 2];
            zv[3] = (f16)nodes[r * 3 + 0]; zv[4] = (f16)nodes[r * 3 + 1]; zv[5] = (f16)nodes[r * 3 + 2];
            zv[6] = (f16)ev.x; zv[7] = (f16)ev.y;
        } else if (c == 1) {
            const float2 ev = *(const float2*)(edges + (size_t)(e0 + e) * 4 + 2);
            zv[0] = (f16)ev.x; zv[1] = (f16)ev.y;
        }
        *(f16x8*)(buf + e * 256 + ((c ^ (e & 7)) << 3)) = zv;
    }
    __syncthreads();

    mlayerR< 32, 256, 0, 1>(buf, 0, 0, wt + WT_MW0, mb0, nullptr, nullptr, nullptr, nullptr, tid);
    __syncthreads();
    mlayerR<256, 256, 0, 1>(buf, 0, 0, wt + WT_MW1, mb1, nullptr, nullptr, nullptr, nullptr, tid);
    __syncthreads();
    mlayerR<256, 128, 0, 1>(buf, 0, 0, wt + WT_MW2, mb2, nullptr, nullptr, nullptr, nullptr, tid);
    __syncthreads();
    mlayerR<128, 128, 0, 0>(buf, 0, 128, wt + WT_AW0, ab0, nullptr, nullptr, nullptr, nullptr, tid);
    __syncthreads();
    mlayerR<128, 128, 1, 0>(buf, 128, 0, wt + WT_AW1, ab1, aw2, lpart, nullptr, nullptr, tid);
    __syncthreads();

    // finalize logits (wave 0) while other waves start VW0 (reads q only)
    if (tid < 64) {
        float wv = lpart[tid] + lpart[64 + tid] + lpart[128 + tid] + lpart[192 + tid] + ab2[0];
        int r = receivers[e0 + tid];
        int pos = atomicAdd(&cursor[r], 1);
        spos[tid] = pos;
        wlog[pos] = wv;
    }
    mlayerR<128, 256, 0, 1>(buf, 0, 0, wt + WT_VW0, vb0, nullptr, nullptr, nullptr, nullptr, tid);
    __syncthreads();   // also makes spos visible before VW1 reads it
    mlayerR<256, 128, 2, 0>(buf, 0, 0, wt + WT_VW1, vb1, nullptr, nullptr, vout, spos, tid);
}

// ---- K2: per-node segmented softmax + weighted aggregation ----
// 4 edges x 128 feats per iteration (1KB/wave/iter); lane (quad,l15) owns
// edge-slot quad, feature octet l15; cross-quad shfl reduce at the end.
__global__ __launch_bounds__(256) void aggregate_kernel(
        const float* __restrict__ wlog, const f16* __restrict__ v,
        const int* __restrict__ base, float* __restrict__ aggr)
{
    const int tid = threadIdx.x;
    const int n = blockIdx.x * 4 + (tid >> 6);
    const int lane = tid & 63;
    const int l15  = lane & 15;
    const int quad = lane >> 4;
    const int st = base[n];
    const int en = (n == NN_NODE - 1) ? NN_EDGE : base[n + 1];

    float mx = -1e9f;
    for (int i = st + lane; i < en; i += 64) mx = fmaxf(mx, wlog[i]);
#pragma unroll
    for (int d = 1; d < 64; d <<= 1) mx = fmaxf(mx, __shfl_xor(mx, d));

    float sm = 0.f;
    for (int i = st + lane; i < en; i += 64) sm += __expf(wlog[i] - mx);
#pragma unroll
    for (int d = 1; d < 64; d <<= 1) sm += __shfl_xor(sm, d);
    const float inv = 1.f / (sm + 1e-12f);

    float a0 = 0.f, a1 = 0.f, a2 = 0.f, a3 = 0.f;
    float a4 = 0.f, a5 = 0.f, a6 = 0.f, a7 = 0.f;
    for (int i = st + quad; i < en; i += 4) {
        float attn = __expf(wlog[i] - mx) * inv;
        f16x8 vv = *(const f16x8*)(v + (size_t)i * 128 + l15 * 8);
        a0 += attn * (float)vv[0];
        a1 += attn * (float)vv[1];
        a2 += attn * (float)vv[2];
        a3 += attn * (float)vv[3];
        a4 += attn * (float)vv[4];
        a5 += attn * (float)vv[5];
        a6 += attn * (float)vv[6];
        a7 += attn * (float)vv[7];
    }
    a0 += __shfl_xor(a0, 16); a0 += __shfl_xor(a0, 32);
    a1 += __shfl_xor(a1, 16); a1 += __shfl_xor(a1, 32);
    a2 += __shfl_xor(a2, 16); a2 += __shfl_xor(a2, 32);
    a3 += __shfl_xor(a3, 16); a3 += __shfl_xor(a3, 32);
    a4 += __shfl_xor(a4, 16); a4 += __shfl_xor(a4, 32);
    a5 += __shfl_xor(a5, 16); a5 += __shfl_xor(a5, 32);
    a6 += __shfl_xor(a6, 16); a6 += __shfl_xor(a6, 32);
    a7 += __shfl_xor(a7, 16); a7 += __shfl_xor(a7, 32);
    if (quad == 0) {
        float4 o0; o0.x = a0; o0.y = a1; o0.z = a2; o0.w = a3;
        float4 o1; o1.x = a4; o1.y = a5; o1.z = a6; o1.w = a7;
        float* dst = aggr + (size_t)n * 128 + l15 * 8;
        *(float4*)(dst + 0) = o0;
        *(float4*)(dst + 4) = o1;
    }
}

// ---- K3: node decoder (64-node tiles) ----
__global__ __launch_bounds__(256, 2) void node_kernel(
        const float* __restrict__ aggr, const f16* __restrict__ wt,
        const float* __restrict__ ub0, const float* __restrict__ ub1,
        const float* __restrict__ uw2, const float* __restrict__ ub2,
        float* __restrict__ out)
{
    __shared__ f16 ldsbuf[2 * 64 * 256];
    f16* bufA = ldsbuf;
    f16* bufB = ldsbuf + 64 * 256;
    const int tid = threadIdx.x;
    const int n0 = blockIdx.x * 64;
    {
        int row = tid >> 2, j = tid & 3;
        int n = n0 + row;
        if (n < NN_NODE) {
            const float4* src = (const float4*)(aggr + (size_t)n * 128 + j * 32);
#pragma unroll
            for (int i = 0; i < 8; ++i) {
                float4 t4 = src[i];
                int c = j * 32 + i * 4;
                bufA[swz(row, c + 0)] = (f16)t4.x;
                bufA[swz(row, c + 1)] = (f16)t4.y;
                bufA[swz(row, c + 2)] = (f16)t4.z;
                bufA[swz(row, c + 3)] = (f16)t4.w;
            }
        } else {
#pragma unroll
            for (int i = 0; i < 32; ++i) bufA[swz(row, j * 32 + i)] = (f16)0.f;
        }
    }
    __syncthreads();
    mfma_layer_basic<128, 256>(bufA, 0, wt + WT_UW0, ub0, bufB, 0, tid); __syncthreads();
    mfma_layer_basic<256, 256>(bufB, 0, wt + WT_UW1, ub1, bufA, 0, tid); __syncthreads();
    {
        int e = tid >> 2, part = tid & 3;
        float sum = 0.f;
        for (int c = part * 64; c < part * 64 + 64; ++c)
            sum += (float)bufA[swz(e, c)] * uw2[c];
        sum += __shfl_down(sum, 2);
        sum += __shfl_down(sum, 1);
        int n = n0 + e;
        if (part == 0 && n < NN_NODE) out[n] = sum + ub2[0];
    }
}

extern "C" void kernel_launch(void* const* d_in, const int* in_sizes, int n_in,
                              void* d_out, int out_size, void* d_ws, size_t ws_size,
                              hipStream_t stream)
{
    const float* nodes     = (const float*)d_in[0];
    const float* edges     = (const float*)d_in[1];
    const int*   senders   = (const int*)d_in[2];
    const int*   receivers = (const int*)d_in[3];
    const float* mw0 = (const float*)d_in[4];  const float* mb0 = (const float*)d_in[5];
    const float* mw1 = (const float*)d_in[6];  const float* mb1 = (const float*)d_in[7];
    const float* mw2 = (const float*)d_in[8];  const float* mb2 = (const float*)d_in[9];
    const float* aw0 = (const float*)d_in[10]; const float* ab0 = (const float*)d_in[11];
    const float* aw1 = (const float*)d_in[12]; const float* ab1 = (const float*)d_in[13];
    const float* aw2 = (const float*)d_in[14]; const float* ab2 = (const float*)d_in[15];
    const float* vw0 = (const float*)d_in[16]; const float* vb0 = (const float*)d_in[17];
    const float* vw1 = (const float*)d_in[18]; const float* vb1 = (const float*)d_in[19];
    const float* uw0 = (const float*)d_in[20]; const float* ub0 = (const float*)d_in[21];
    const float* uw1 = (const float*)d_in[22]; const float* ub1 = (const float*)d_in[23];
    const float* uw2 = (const float*)d_in[24]; const float* ub2 = (const float*)d_in[25];

    char* ws = (char*)d_ws;
    f16*   wt   = (f16*)ws;
    f16*   vbuf = (f16*)(ws + V_OFF);
    float* wlog = (float*)(ws + WL_OFF);
    int*   cnt  = (int*)(ws + CNT_OFF);
    int*   base = (int*)(ws + BASE_OFF);
    float* aggr = (float*)(ws + AGGR_OFF);
    float* out  = (float*)d_out;

    hipMemsetAsync(cnt, 0, NN_NODE * sizeof(int), stream);

    WSegs segs = {{
        { mw0,  10, 256,  32, WT_MW0 },
        { mw1, 256, 256, 256, WT_MW1 },
        { mw2, 256, 128, 256, WT_MW2 },
        { aw0, 128, 128, 128, WT_AW0 },
        { aw1, 128, 128, 128, WT_AW1 },
        { vw0, 128, 256, 128, WT_VW0 },
        { vw1, 256, 128, 256, WT_VW1 },
        { uw0, 128, 256, 128, WT_UW0 },
        { uw1, 256, 256, 256, WT_UW1 },
    }};
    prep_kernel<<<(WT_TOTAL + 255) / 256, 256, 0, stream>>>(segs, wt);

    hist_kernel<<<NN_EDGE / 256, 256, 0, stream>>>(receivers, cnt);
    scan_kernel<<<1, 1024, 0, stream>>>(cnt, base);

    edge_kernel<<<NN_EDGE / 64, 256, 0, stream>>>(nodes, edges, senders, receivers, wt,
        mb0, mb1, mb2, ab0, ab1, aw2, ab2, vb0, vb1, vbuf, wlog, cnt);

    aggregate_kernel<<<NN_NODE / 4, 256, 0, stream>>>(wlog, vbuf, base, aggr);

    node_kernel<<<(NN_NODE + 63) / 64, 256, 0, stream>>>(aggr, wt, ub0, ub1, uw2, ub2, out);
}